// Round 11
// baseline (787.893 us; speedup 1.0000x reference)
//
#include <hip/hip_runtime.h>

#define NN 100000
#define NE 1600000
#define NB_SCAN 391   // ceil(NN/256)

// ---------------- bf16 helpers (manual, RNE) ----------------
__device__ inline float b2f(unsigned short u) {
  return __uint_as_float(((unsigned)u) << 16);
}
__device__ inline unsigned short f2b(float f) {
  unsigned x = __float_as_uint(f);
  unsigned r = (x + 0x7fffu + ((x >> 16) & 1u)) >> 16;
  return (unsigned short)r;
}
__device__ inline float ulo(unsigned u) { return __uint_as_float(u << 16); }
__device__ inline float uhi(unsigned u) { return __uint_as_float(u & 0xffff0000u); }
__device__ inline unsigned packb(float lo, float hi) {
  return (unsigned)f2b(lo) | ((unsigned)f2b(hi) << 16);
}

// ---------------- CSR build ----------------

__global__ void count_rank_kernel(const int* __restrict__ dst, int* __restrict__ counts,
                                  int* __restrict__ rank) {
  int i = blockIdx.x * blockDim.x + threadIdx.x;
  int st = gridDim.x * blockDim.x;
  for (; i < NE; i += st) rank[i] = atomicAdd(&counts[dst[i]], 1);
}

__global__ void scan1_kernel(const int* __restrict__ counts, int* __restrict__ offsets,
                             int* __restrict__ blocksum, float* __restrict__ dinv) {
  __shared__ int s[256];
  int t = threadIdx.x;
  int i = blockIdx.x * 256 + t;
  int v = (i < NN) ? counts[i] : 0;
  s[t] = v; __syncthreads();
  for (int off = 1; off < 256; off <<= 1) {
    int x = 0;
    if (t >= off) x = s[t - off];
    __syncthreads();
    if (t >= off) s[t] += x;
    __syncthreads();
  }
  if (i < NN) {
    offsets[i] = s[t] - v;
    dinv[i] = rsqrtf((float)v + 1.0f);
  }
  if (t == 255) blocksum[blockIdx.x] = s[255];
}

__global__ void scan2_kernel(const int* __restrict__ blocksum, int* __restrict__ blockpfx,
                             int* __restrict__ offsets) {
  __shared__ int s[512];
  int t = threadIdx.x;
  int v = (t < NB_SCAN) ? blocksum[t] : 0;
  s[t] = v; __syncthreads();
  for (int off = 1; off < 512; off <<= 1) {
    int x = 0;
    if (t >= off) x = s[t - off];
    __syncthreads();
    if (t >= off) s[t] += x;
    __syncthreads();
  }
  if (t < NB_SCAN) blockpfx[t] = s[t] - v;
  if (t == 511) offsets[NN] = s[511];
}

__global__ void scan3_kernel(int* __restrict__ offsets, const int* __restrict__ blockpfx) {
  int i = blockIdx.x * 256 + threadIdx.x;
  if (i < NN) offsets[i] += blockpfx[i >> 8];
}

__global__ void scatter_kernel(const int* __restrict__ src, const int* __restrict__ dst,
                               const int* __restrict__ offsets, const int* __restrict__ rank,
                               int* __restrict__ src_s) {
  int i = blockIdx.x * blockDim.x + threadIdx.x;
  int st = gridDim.x * blockDim.x;
  for (; i < NE; i += st) {
    int d = dst[i];
    src_s[offsets[d] + rank[i]] = src[i];
  }
}

// ---------------- fold input Linear into layer-0 weight ----------------
__global__ void foldw_kernel(const float* __restrict__ W_in, const float* __restrict__ b_in,
                             const float* __restrict__ W0,
                             float* __restrict__ Wc, float* __restrict__ bc) {
  int t = threadIdx.x;
  for (int e = t; e < 4096; e += 256) {
    int i = e >> 6, j = e & 63;
    float s = 0.f;
#pragma unroll
    for (int k = 0; k < 64; ++k) s += W_in[i * 64 + k] * W0[k * 64 + j];
    Wc[e] = s;
  }
  if (t < 64) {
    float s = 0.f;
#pragma unroll
    for (int k = 0; k < 64; ++k) s += b_in[k] * W0[k * 64 + t];
    bc[t] = s;
  }
}

// ---------------- persistent GEMM 64x64: stage W once, grid-stride tiles ----------------

__global__ __launch_bounds__(256) void gemm64_kernel(
    const void* __restrict__ xin, int xbf16,
    const float* __restrict__ W, const float* __restrict__ bias,
    const float* __restrict__ bnac, const float* __restrict__ rowscale,
    unsigned short* __restrict__ out16) {
  __shared__ float sW[64][64];
  __shared__ float sx[16][64];
  int t = threadIdx.x;
  int col = t & 63;
  int rw = t >> 6;
#pragma unroll
  for (int j = 0; j < 16; ++j) {
    int e = t + 256 * j;
    sW[e >> 6][col] = W[e];
  }
  float a = 1.f, c = 0.f;
  if (bnac) { a = bnac[col]; c = bnac[64 + col]; }
  float bv = bias ? bias[col] : 0.f;
  const float* xf = (const float*)xin;
  const unsigned short* xh = (const unsigned short*)xin;
  int ntile = (NN + 15) >> 4;
  for (int tile = blockIdx.x; tile < ntile; tile += gridDim.x) {
    int row0 = tile << 4;
    __syncthreads();
#pragma unroll
    for (int j = 0; j < 4; ++j) {
      int e = t + 256 * j;
      int r = e >> 6;
      int grow = row0 + r;
      float v = 0.f;
      if (grow < NN)
        v = xbf16 ? b2f(xh[(size_t)grow * 64 + col]) : xf[(size_t)grow * 64 + col];
      if (bnac) v = fmaxf(fmaf(v, a, c), 0.f);
      sx[r][col] = v;
    }
    __syncthreads();
    float acc0 = 0, acc1 = 0, acc2 = 0, acc3 = 0;
#pragma unroll 4
    for (int k = 0; k < 64; k += 4) {
      float4 x0 = *(const float4*)&sx[rw * 4 + 0][k];
      float4 x1 = *(const float4*)&sx[rw * 4 + 1][k];
      float4 x2 = *(const float4*)&sx[rw * 4 + 2][k];
      float4 x3 = *(const float4*)&sx[rw * 4 + 3][k];
      float w0 = sW[k + 0][col], w1 = sW[k + 1][col];
      float w2 = sW[k + 2][col], w3 = sW[k + 3][col];
      acc0 = fmaf(x0.w, w3, fmaf(x0.z, w2, fmaf(x0.y, w1, fmaf(x0.x, w0, acc0))));
      acc1 = fmaf(x1.w, w3, fmaf(x1.z, w2, fmaf(x1.y, w1, fmaf(x1.x, w0, acc1))));
      acc2 = fmaf(x2.w, w3, fmaf(x2.z, w2, fmaf(x2.y, w1, fmaf(x2.x, w0, acc2))));
      acc3 = fmaf(x3.w, w3, fmaf(x3.z, w2, fmaf(x3.y, w1, fmaf(x3.x, w0, acc3))));
    }
    int r0 = row0 + rw * 4;
#pragma unroll
    for (int r = 0; r < 4; ++r) {
      int grow = r0 + r;
      if (grow < NN) {
        float acc = (r == 0) ? acc0 : (r == 1) ? acc1 : (r == 2) ? acc2 : acc3;
        out16[(size_t)grow * 64 + col] = f2b((acc + bv) * rowscale[grow]);
      }
    }
  }
}

// ---------------- Edge aggregation: uint lanes (2ch), 2 rows/instr, 32 rows in flight ----
// lane: half = lane>>5 (edge-slot parity), cl = lane&31 (channel pair 2cl,2cl+1).

__device__ __forceinline__ void agg_slow_u(
    const unsigned* __restrict__ xp32, const int* __restrict__ src_s,
    int beg, int end, int lane, int half, int cl,
    float& x0, float& y0, float& x1, float& y1) {
  int deg = end - beg, done = 0;
  while (done < deg) {
    int chunk = deg - done;
    if (chunk > 64) chunk = 64;
    int idx = (lane < chunk) ? src_s[beg + done + lane] : 0;
    for (int k = 0; 2 * k < chunk; ++k) {
      int e = 2 * k + half;
      int r = __shfl(idx, e);
      unsigned u = xp32[(size_t)r * 32 + cl];
      if (e >= chunk) u = 0u;
      if (k & 1) { x1 += ulo(u); y1 += uhi(u); }
      else       { x0 += ulo(u); y0 += uhi(u); }
    }
    done += chunk;
  }
}

__global__ __launch_bounds__(256) void agg_kernel(
    const unsigned* __restrict__ xp32, const int* __restrict__ offsets,
    const int* __restrict__ src_s, const float* __restrict__ dinv,
    const float* __restrict__ bvec, unsigned* __restrict__ h2u,
    float* __restrict__ bnacc) {
  int t = threadIdx.x;
  int lane = t & 63;
  int wv = t >> 6;
  int half = lane >> 5;
  int cl = lane & 31;
  float2 bias2 = ((const float2*)bvec)[cl];
  float s1x = 0, s1y = 0, s2x = 0, s2y = 0;
  int gw = blockIdx.x * 4 + wv;
  int nw = gridDim.x * 4;
  const int NP = NN / 2;
  for (int p = gw; p < NP; p += nw) {
    int nA = 2 * p, nB = 2 * p + 1;
    int begA = offsets[nA], begB = offsets[nA + 1], endB = offsets[nA + 2];
    int degA = begB - begA, degB = endB - begB;
    float ax0 = 0, ay0 = 0, ax1 = 0, ay1 = 0;
    float bx0 = 0, by0 = 0, bx1 = 0, by1 = 0;
    // self terms: half0 lanes take node A's row, half1 node B's
    {
      unsigned su = xp32[(size_t)(half ? nB : nA) * 32 + cl];
      float lo = ulo(su), hi = uhi(su);
      if (half == 0) { ax0 += lo; ay0 += hi; }
      else           { bx0 += lo; by0 += hi; }
    }
    if (degA <= 64 && degB <= 64) {
      int idxA = (lane < degA) ? src_s[begA + lane] : 0;
      int idxB = (lane < degB) ? src_s[begB + lane] : 0;
      for (int e0 = 0; e0 < 64; e0 += 16) {
        bool doA = e0 < degA, doB = e0 < degB;
        if (!(doA || doB)) break;
        unsigned uA[8], uB[8];
        if (doA) {
#pragma unroll
          for (int m = 0; m < 8; ++m) {
            int e = e0 + 2 * m + half;
            int r = __shfl(idxA, e);
            uA[m] = xp32[(size_t)r * 32 + cl];
          }
        }
        if (doB) {
#pragma unroll
          for (int m = 0; m < 8; ++m) {
            int e = e0 + 2 * m + half;
            int r = __shfl(idxB, e);
            uB[m] = xp32[(size_t)r * 32 + cl];
          }
        }
        if (doA) {
#pragma unroll
          for (int m = 0; m < 8; ++m) {
            int e = e0 + 2 * m + half;
            unsigned u = (e < degA) ? uA[m] : 0u;
            if (m & 1) { ax1 += ulo(u); ay1 += uhi(u); }
            else       { ax0 += ulo(u); ay0 += uhi(u); }
          }
        }
        if (doB) {
#pragma unroll
          for (int m = 0; m < 8; ++m) {
            int e = e0 + 2 * m + half;
            unsigned u = (e < degB) ? uB[m] : 0u;
            if (m & 1) { bx1 += ulo(u); by1 += uhi(u); }
            else       { bx0 += ulo(u); by0 += uhi(u); }
          }
        }
      }
    } else {
      agg_slow_u(xp32, src_s, begA, begB, lane, half, cl, ax0, ay0, ax1, ay1);
      agg_slow_u(xp32, src_s, begB, endB, lane, half, cl, bx0, by0, bx1, by1);
    }
    float vAx = ax0 + ax1, vAy = ay0 + ay1;
    float vBx = bx0 + bx1, vBy = by0 + by1;
    vAx += __shfl_xor(vAx, 32); vAy += __shfl_xor(vAy, 32);
    vBx += __shfl_xor(vBx, 32); vBy += __shfl_xor(vBy, 32);
    float diA = dinv[nA], diB = dinv[nB];
    float fAx = fmaf(vAx, diA, bias2.x), fAy = fmaf(vAy, diA, bias2.y);
    float fBx = fmaf(vBx, diB, bias2.x), fBy = fmaf(vBy, diB, bias2.y);
    // write: half0 lanes write node A, half1 write node B (bf16x2)
    unsigned pk = half ? packb(fBx, fBy) : packb(fAx, fAy);
    h2u[(size_t)(half ? nB : nA) * 32 + cl] = pk;
    // stats: half0 counts node A, half1 counts node B (fp32, pre-rounding)
    float sx_ = half ? fBx : fAx, sy_ = half ? fBy : fAy;
    s1x += sx_; s1y += sy_;
    s2x += sx_ * sx_; s2y += sy_ * sy_;
  }
  s1x += __shfl_xor(s1x, 32); s1y += __shfl_xor(s1y, 32);
  s2x += __shfl_xor(s2x, 32); s2y += __shfl_xor(s2y, 32);
  __shared__ float ls[4][4][32];
  if (lane < 32) {
    ls[wv][0][cl] = s1x; ls[wv][1][cl] = s1y;
    ls[wv][2][cl] = s2x; ls[wv][3][cl] = s2y;
  }
  __syncthreads();
  if (t < 32) {
    float A = 0, B = 0, C = 0, D = 0;
#pragma unroll
    for (int w = 0; w < 4; ++w) {
      A += ls[w][0][t]; B += ls[w][1][t];
      C += ls[w][2][t]; D += ls[w][3][t];
    }
    atomicAdd(&bnacc[2 * t], A);
    atomicAdd(&bnacc[2 * t + 1], B);
    atomicAdd(&bnacc[64 + 2 * t], C);
    atomicAdd(&bnacc[64 + 2 * t + 1], D);
  }
}

// BN finalize -> affine form: a = gamma*istd, c = beta - mean*a
__global__ void bn_finalize_kernel(const float* __restrict__ bnacc,
                                   const float* __restrict__ gamma,
                                   const float* __restrict__ beta,
                                   float* __restrict__ bnac) {
  int ch = threadIdx.x;  // 64 threads
  float mean = bnacc[ch] * (1.0f / NN);
  float var = bnacc[64 + ch] * (1.0f / NN) - mean * mean;
  float istd = rsqrtf(var + 1e-5f);
  float a = gamma[ch] * istd;
  bnac[ch] = a;
  bnac[64 + ch] = beta[ch] - mean * a;
}

// ---------------- persistent Output MLP: affine-BN -> Lin(64,128)+ReLU -> Lin(128,1) ----

__global__ __launch_bounds__(256) void out_kernel(
    const unsigned short* __restrict__ x, const float* __restrict__ bnac,
    const float* __restrict__ W1, const float* __restrict__ b1,
    const float* __restrict__ W2, const float* __restrict__ b2,
    float* __restrict__ out) {
  __shared__ float sW1[64][128];
  __shared__ float sx[16][64];
  __shared__ float sz[16][128];
  __shared__ float sW2[128];
  int t = threadIdx.x;
#pragma unroll
  for (int j = 0; j < 32; ++j) {
    int e = t + 256 * j;
    sW1[e >> 7][e & 127] = W1[e];
  }
  if (t < 128) sW2[t] = W2[t];
  int c64 = t & 63;
  float a = bnac[c64], c = bnac[64 + c64];
  int col = t & 127;
  int rg = t >> 7;
  float b1v = b1[col];
  float b2v = b2[0];
  int ntile = (NN + 15) >> 4;
  for (int tile = blockIdx.x; tile < ntile; tile += gridDim.x) {
    int row0 = tile << 4;
    __syncthreads();
#pragma unroll
    for (int j = 0; j < 4; ++j) {
      int e = t + 256 * j;
      int r = e >> 6;
      int grow = row0 + r;
      float v = (grow < NN) ? b2f(x[(size_t)grow * 64 + c64]) : 0.f;
      sx[r][c64] = fmaf(v, a, c);   // BN, no ReLU (last layer)
    }
    __syncthreads();
    float acc[8];
#pragma unroll
    for (int r = 0; r < 8; ++r) acc[r] = 0.f;
#pragma unroll 4
    for (int k = 0; k < 64; k += 4) {
      float w0 = sW1[k + 0][col], w1 = sW1[k + 1][col];
      float w2 = sW1[k + 2][col], w3 = sW1[k + 3][col];
#pragma unroll
      for (int r = 0; r < 8; ++r) {
        float4 xv = *(const float4*)&sx[rg * 8 + r][k];
        acc[r] = fmaf(xv.w, w3, fmaf(xv.z, w2, fmaf(xv.y, w1, fmaf(xv.x, w0, acc[r]))));
      }
    }
#pragma unroll
    for (int r = 0; r < 8; ++r) sz[rg * 8 + r][col] = fmaxf(acc[r] + b1v, 0.f);
    __syncthreads();
    {
      int row = t >> 4, g = t & 15;
      const float4* zr = (const float4*)&sz[row][0];
      const float4* wp = (const float4*)sW2;
      float4 z0 = zr[g * 2], z1 = zr[g * 2 + 1];
      float4 w0 = wp[g * 2], w1 = wp[g * 2 + 1];
      float p = z0.x * w0.x + z0.y * w0.y + z0.z * w0.z + z0.w * w0.w
              + z1.x * w1.x + z1.y * w1.y + z1.z * w1.z + z1.w * w1.w;
      p += __shfl_down(p, 8);
      p += __shfl_down(p, 4);
      p += __shfl_down(p, 2);
      p += __shfl_down(p, 1);
      int grow = row0 + row;
      if (g == 0 && grow < NN) out[grow] = p + b2v;
    }
  }
}

// ---------------- launch ----------------

extern "C" void kernel_launch(void* const* d_in, const int* in_sizes, int n_in,
                              void* d_out, int out_size, void* d_ws, size_t ws_size,
                              hipStream_t stream) {
  const float* X = (const float*)d_in[0];
  const int* edge = (const int*)d_in[1];
  const int* esrc = edge;
  const int* edst = edge + NE;
  const float* W_in = (const float*)d_in[2];
  const float* b_in = (const float*)d_in[3];
  const float* Ws = (const float*)d_in[4];
  const float* bs = (const float*)d_in[5];
  const float* gammas = (const float*)d_in[6];
  const float* betas = (const float*)d_in[7];
  const float* W1 = (const float*)d_in[8];
  const float* b1 = (const float*)d_in[9];
  const float* W2 = (const float*)d_in[10];
  const float* b2 = (const float*)d_in[11];
  float* out = (float*)d_out;

  char* base = (char*)d_ws;
  size_t o = 0;
  auto alloc = [&](size_t bytes) {
    o = (o + 255) & ~(size_t)255;
    void* p = base + o;
    o += bytes;
    return p;
  };
  int* counts = (int*)alloc((size_t)NN * 4);
  int* offsets = (int*)alloc((size_t)(NN + 1) * 4);
  int* blocksum = (int*)alloc(512 * 4);
  int* blockpfx = (int*)alloc(512 * 4);
  int* rank = (int*)alloc((size_t)NE * 4);
  int* src_s = (int*)alloc((size_t)NE * 4);
  float* dinv = (float*)alloc((size_t)NN * 4);
  unsigned short* bufA = (unsigned short*)alloc((size_t)NN * 64 * 2);
  unsigned short* bufB = (unsigned short*)alloc((size_t)NN * 64 * 2);
  unsigned short* hbuf16 = (unsigned short*)alloc((size_t)NN * 64 * 2);
  float* bnacc = (float*)alloc(3 * 128 * 4);
  float* bnpar = (float*)alloc(3 * 128 * 4);
  float* Wc = (float*)alloc(4096 * 4);
  float* bc = (float*)alloc(64 * 4);

  hipMemsetAsync(counts, 0, (size_t)NN * 4, stream);
  hipMemsetAsync(bnacc, 0, 3 * 128 * 4, stream);

  foldw_kernel<<<1, 256, 0, stream>>>(W_in, b_in, Ws, Wc, bc);
  count_rank_kernel<<<2048, 256, 0, stream>>>(edst, counts, rank);
  scan1_kernel<<<NB_SCAN, 256, 0, stream>>>(counts, offsets, blocksum, dinv);
  scan2_kernel<<<1, 512, 0, stream>>>(blocksum, blockpfx, offsets);
  scan3_kernel<<<NB_SCAN, 256, 0, stream>>>(offsets, blockpfx);
  scatter_kernel<<<2048, 256, 0, stream>>>(esrc, edst, offsets, rank, src_s);

  unsigned short* xbufs[2] = {bufA, bufB};
  const unsigned short* xcur = nullptr;
  for (int i = 0; i < 3; ++i) {
    if (i == 0) {
      gemm64_kernel<<<1024, 256, 0, stream>>>(X, 0, Wc, bc, nullptr, dinv, hbuf16);
    } else {
      gemm64_kernel<<<1024, 256, 0, stream>>>(xcur, 1, Ws + (size_t)i * 64 * 64, nullptr,
                                              bnpar + (size_t)(i - 1) * 128,
                                              dinv, hbuf16);
    }
    unsigned short* xnext = xbufs[i & 1];
    agg_kernel<<<2048, 256, 0, stream>>>((const unsigned*)hbuf16, offsets, src_s, dinv,
                                         bs + (size_t)i * 64, (unsigned*)xnext,
                                         bnacc + (size_t)i * 128);
    bn_finalize_kernel<<<1, 64, 0, stream>>>(bnacc + (size_t)i * 128,
                                             gammas + (size_t)i * 64,
                                             betas + (size_t)i * 64,
                                             bnpar + (size_t)i * 128);
    xcur = xnext;
  }
  out_kernel<<<1024, 256, 0, stream>>>(xcur, bnpar + 2 * 128, W1, b1, W2, b2, out);
}

// Round 12
// 630.153 us; speedup vs baseline: 1.2503x; 1.2503x over previous
//
#include <hip/hip_runtime.h>

#define NN 100000
#define NE 1600000
#define NB_SCAN 391   // ceil(NN/256)

// ---------------- bf16 helpers (manual, RNE) ----------------
__device__ inline float b2f(unsigned short u) {
  return __uint_as_float(((unsigned)u) << 16);
}
__device__ inline unsigned short f2b(float f) {
  unsigned x = __float_as_uint(f);
  unsigned r = (x + 0x7fffu + ((x >> 16) & 1u)) >> 16;
  return (unsigned short)r;
}

// ---------------- CSR build ----------------

__global__ void count_rank_kernel(const int* __restrict__ dst, int* __restrict__ counts,
                                  int* __restrict__ rank) {
  int i = blockIdx.x * blockDim.x + threadIdx.x;
  int st = gridDim.x * blockDim.x;
  for (; i < NE; i += st) rank[i] = atomicAdd(&counts[dst[i]], 1);
}

__global__ void scan1_kernel(const int* __restrict__ counts, int* __restrict__ offsets,
                             int* __restrict__ blocksum, float* __restrict__ dinv) {
  __shared__ int s[256];
  int t = threadIdx.x;
  int i = blockIdx.x * 256 + t;
  int v = (i < NN) ? counts[i] : 0;
  s[t] = v; __syncthreads();
  for (int off = 1; off < 256; off <<= 1) {
    int x = 0;
    if (t >= off) x = s[t - off];
    __syncthreads();
    if (t >= off) s[t] += x;
    __syncthreads();
  }
  if (i < NN) {
    offsets[i] = s[t] - v;
    dinv[i] = rsqrtf((float)v + 1.0f);
  }
  if (t == 255) blocksum[blockIdx.x] = s[255];
}

__global__ void scan2_kernel(const int* __restrict__ blocksum, int* __restrict__ blockpfx,
                             int* __restrict__ offsets) {
  __shared__ int s[512];
  int t = threadIdx.x;
  int v = (t < NB_SCAN) ? blocksum[t] : 0;
  s[t] = v; __syncthreads();
  for (int off = 1; off < 512; off <<= 1) {
    int x = 0;
    if (t >= off) x = s[t - off];
    __syncthreads();
    if (t >= off) s[t] += x;
    __syncthreads();
  }
  if (t < NB_SCAN) blockpfx[t] = s[t] - v;
  if (t == 511) offsets[NN] = s[511];
}

__global__ void scan3_kernel(int* __restrict__ offsets, const int* __restrict__ blockpfx) {
  int i = blockIdx.x * 256 + threadIdx.x;
  if (i < NN) offsets[i] += blockpfx[i >> 8];
}

__global__ void scatter_kernel(const int* __restrict__ src, const int* __restrict__ dst,
                               const int* __restrict__ offsets, const int* __restrict__ rank,
                               int* __restrict__ src_s) {
  int i = blockIdx.x * blockDim.x + threadIdx.x;
  int st = gridDim.x * blockDim.x;
  for (; i < NE; i += st) {
    int d = dst[i];
    src_s[offsets[d] + rank[i]] = src[i];
  }
}

// ---------------- fold input Linear into layer-0 weight ----------------
__global__ void foldw_kernel(const float* __restrict__ W_in, const float* __restrict__ b_in,
                             const float* __restrict__ W0,
                             float* __restrict__ Wc, float* __restrict__ bc) {
  int t = threadIdx.x;
  for (int e = t; e < 4096; e += 256) {
    int i = e >> 6, j = e & 63;
    float s = 0.f;
#pragma unroll
    for (int k = 0; k < 64; ++k) s += W_in[i * 64 + k] * W0[k * 64 + j];
    Wc[e] = s;
  }
  if (t < 64) {
    float s = 0.f;
#pragma unroll
    for (int k = 0; k < 64; ++k) s += b_in[k] * W0[k * 64 + t];
    bc[t] = s;
  }
}

// ---------------- GEMM 64x64: broadcast-b128 LDS reads, fused affine-BN+ReLU, bf16 out ----

__global__ __launch_bounds__(256) void gemm64_kernel(
    const void* __restrict__ xin, int xbf16,
    const float* __restrict__ W, const float* __restrict__ bias,
    const float* __restrict__ bnac, const float* __restrict__ rowscale,
    unsigned short* __restrict__ out16) {
  __shared__ float sW[64][64];
  __shared__ float sx[16][64];
  int t = threadIdx.x;
  int col = t & 63;
  int rw = t >> 6;
  int row0 = blockIdx.x * 16;

#pragma unroll
  for (int j = 0; j < 16; ++j) {
    int e = t + 256 * j;
    sW[e >> 6][col] = W[e];
  }
  float a = 1.f, c = 0.f;
  if (bnac) { a = bnac[col]; c = bnac[64 + col]; }
  const float* xf = (const float*)xin;
  const unsigned short* xh = (const unsigned short*)xin;
#pragma unroll
  for (int j = 0; j < 4; ++j) {
    int e = t + 256 * j;
    int r = e >> 6;
    int grow = row0 + r;
    float v = 0.f;
    if (grow < NN)
      v = xbf16 ? b2f(xh[(size_t)grow * 64 + col]) : xf[(size_t)grow * 64 + col];
    if (bnac) v = fmaxf(fmaf(v, a, c), 0.f);
    sx[r][col] = v;
  }
  __syncthreads();

  float acc0 = 0, acc1 = 0, acc2 = 0, acc3 = 0;
#pragma unroll 4
  for (int k = 0; k < 64; k += 4) {
    float4 x0 = *(const float4*)&sx[rw * 4 + 0][k];
    float4 x1 = *(const float4*)&sx[rw * 4 + 1][k];
    float4 x2 = *(const float4*)&sx[rw * 4 + 2][k];
    float4 x3 = *(const float4*)&sx[rw * 4 + 3][k];
    float w0 = sW[k + 0][col], w1 = sW[k + 1][col];
    float w2 = sW[k + 2][col], w3 = sW[k + 3][col];
    acc0 = fmaf(x0.w, w3, fmaf(x0.z, w2, fmaf(x0.y, w1, fmaf(x0.x, w0, acc0))));
    acc1 = fmaf(x1.w, w3, fmaf(x1.z, w2, fmaf(x1.y, w1, fmaf(x1.x, w0, acc1))));
    acc2 = fmaf(x2.w, w3, fmaf(x2.z, w2, fmaf(x2.y, w1, fmaf(x2.x, w0, acc2))));
    acc3 = fmaf(x3.w, w3, fmaf(x3.z, w2, fmaf(x3.y, w1, fmaf(x3.x, w0, acc3))));
  }
  float bv = bias ? bias[col] : 0.f;
  int r0 = row0 + rw * 4;
#pragma unroll
  for (int r = 0; r < 4; ++r) {
    int grow = r0 + r;
    if (grow < NN) {
      float acc = (r == 0) ? acc0 : (r == 1) ? acc1 : (r == 2) ? acc2 : acc3;
      out16[(size_t)grow * 64 + col] = f2b((acc + bv) * rowscale[grow]);
    }
  }
}

// ---------------- Edge aggregation: 2 nodes/wave interleaved, 16 gathers in flight ----
// lane = channel (ushort loads, 128 B contiguous row per instruction). bf16 out.

__device__ __forceinline__ void agg_slow(const unsigned short* __restrict__ xp16,
                                         const int* __restrict__ src_s,
                                         int beg, int end, int lane,
                                         float& a0, float& a1, float& a2, float& a3) {
  int deg = end - beg, done = 0;
  while (done < deg) {
    int chunk = deg - done;
    if (chunk > 64) chunk = 64;
    int idx = (lane < chunk) ? src_s[beg + done + lane] : 0;
    int j = 0;
    for (; j + 4 <= chunk; j += 4) {
      int t0 = __shfl(idx, j + 0), t1 = __shfl(idx, j + 1);
      int t2 = __shfl(idx, j + 2), t3 = __shfl(idx, j + 3);
      a0 += b2f(xp16[(size_t)t0 * 64 + lane]);
      a1 += b2f(xp16[(size_t)t1 * 64 + lane]);
      a2 += b2f(xp16[(size_t)t2 * 64 + lane]);
      a3 += b2f(xp16[(size_t)t3 * 64 + lane]);
    }
    for (; j < chunk; ++j) {
      int s = __shfl(idx, j);
      a0 += b2f(xp16[(size_t)s * 64 + lane]);
    }
    done += chunk;
  }
}

__global__ __launch_bounds__(256) void agg_kernel(
    const unsigned short* __restrict__ xp16, const int* __restrict__ offsets,
    const int* __restrict__ src_s, const float* __restrict__ dinv,
    const float* __restrict__ bvec, unsigned short* __restrict__ h2,
    float* __restrict__ bnacc) {
  int t = threadIdx.x;
  int lane = t & 63;
  int wv = t >> 6;
  float bias = bvec[lane];
  float s1 = 0.f, s2 = 0.f;
  int gw = blockIdx.x * 4 + wv;
  int nw = gridDim.x * 4;
  const int NP = NN / 2;   // 50000 pairs (NN even)
  for (int p = gw; p < NP; p += nw) {
    int nA = 2 * p, nB = 2 * p + 1;
    int begA = offsets[nA];
    int begB = offsets[nA + 1];
    int endB = offsets[nA + 2];
    int degA = begB - begA, degB = endB - begB;
    float a0 = b2f(xp16[(size_t)nA * 64 + lane]), a1 = 0.f, a2 = 0.f, a3 = 0.f;
    float c0 = b2f(xp16[(size_t)nB * 64 + lane]), c1 = 0.f, c2 = 0.f, c3 = 0.f;
    if (degA <= 64 && degB <= 64) {
      int idxA = (lane < degA) ? src_s[begA + lane] : 0;
      int idxB = (lane < degB) ? src_s[begB + lane] : 0;
      int ja = 0, jb = 0;
      // interleaved: 8 from A + 8 from B per iteration -> 16 loads in flight
      while (ja + 8 <= degA && jb + 8 <= degB) {
        int A0 = __shfl(idxA, ja + 0), A1 = __shfl(idxA, ja + 1);
        int A2 = __shfl(idxA, ja + 2), A3 = __shfl(idxA, ja + 3);
        int A4 = __shfl(idxA, ja + 4), A5 = __shfl(idxA, ja + 5);
        int A6 = __shfl(idxA, ja + 6), A7 = __shfl(idxA, ja + 7);
        int B0 = __shfl(idxB, jb + 0), B1 = __shfl(idxB, jb + 1);
        int B2 = __shfl(idxB, jb + 2), B3 = __shfl(idxB, jb + 3);
        int B4 = __shfl(idxB, jb + 4), B5 = __shfl(idxB, jb + 5);
        int B6 = __shfl(idxB, jb + 6), B7 = __shfl(idxB, jb + 7);
        unsigned short uA0 = xp16[(size_t)A0 * 64 + lane];
        unsigned short uA1 = xp16[(size_t)A1 * 64 + lane];
        unsigned short uA2 = xp16[(size_t)A2 * 64 + lane];
        unsigned short uA3 = xp16[(size_t)A3 * 64 + lane];
        unsigned short uA4 = xp16[(size_t)A4 * 64 + lane];
        unsigned short uA5 = xp16[(size_t)A5 * 64 + lane];
        unsigned short uA6 = xp16[(size_t)A6 * 64 + lane];
        unsigned short uA7 = xp16[(size_t)A7 * 64 + lane];
        unsigned short uB0 = xp16[(size_t)B0 * 64 + lane];
        unsigned short uB1 = xp16[(size_t)B1 * 64 + lane];
        unsigned short uB2 = xp16[(size_t)B2 * 64 + lane];
        unsigned short uB3 = xp16[(size_t)B3 * 64 + lane];
        unsigned short uB4 = xp16[(size_t)B4 * 64 + lane];
        unsigned short uB5 = xp16[(size_t)B5 * 64 + lane];
        unsigned short uB6 = xp16[(size_t)B6 * 64 + lane];
        unsigned short uB7 = xp16[(size_t)B7 * 64 + lane];
        a0 += b2f(uA0) + b2f(uA4);  a1 += b2f(uA1) + b2f(uA5);
        a2 += b2f(uA2) + b2f(uA6);  a3 += b2f(uA3) + b2f(uA7);
        c0 += b2f(uB0) + b2f(uB4);  c1 += b2f(uB1) + b2f(uB5);
        c2 += b2f(uB2) + b2f(uB6);  c3 += b2f(uB3) + b2f(uB7);
        ja += 8; jb += 8;
      }
      // drain A
      for (; ja + 8 <= degA; ja += 8) {
        int A0 = __shfl(idxA, ja + 0), A1 = __shfl(idxA, ja + 1);
        int A2 = __shfl(idxA, ja + 2), A3 = __shfl(idxA, ja + 3);
        int A4 = __shfl(idxA, ja + 4), A5 = __shfl(idxA, ja + 5);
        int A6 = __shfl(idxA, ja + 6), A7 = __shfl(idxA, ja + 7);
        unsigned short u0 = xp16[(size_t)A0 * 64 + lane];
        unsigned short u1 = xp16[(size_t)A1 * 64 + lane];
        unsigned short u2 = xp16[(size_t)A2 * 64 + lane];
        unsigned short u3 = xp16[(size_t)A3 * 64 + lane];
        unsigned short u4 = xp16[(size_t)A4 * 64 + lane];
        unsigned short u5 = xp16[(size_t)A5 * 64 + lane];
        unsigned short u6 = xp16[(size_t)A6 * 64 + lane];
        unsigned short u7 = xp16[(size_t)A7 * 64 + lane];
        a0 += b2f(u0) + b2f(u4);  a1 += b2f(u1) + b2f(u5);
        a2 += b2f(u2) + b2f(u6);  a3 += b2f(u3) + b2f(u7);
      }
      for (; ja + 4 <= degA; ja += 4) {
        int A0 = __shfl(idxA, ja + 0), A1 = __shfl(idxA, ja + 1);
        int A2 = __shfl(idxA, ja + 2), A3 = __shfl(idxA, ja + 3);
        a0 += b2f(xp16[(size_t)A0 * 64 + lane]);
        a1 += b2f(xp16[(size_t)A1 * 64 + lane]);
        a2 += b2f(xp16[(size_t)A2 * 64 + lane]);
        a3 += b2f(xp16[(size_t)A3 * 64 + lane]);
      }
      for (; ja < degA; ++ja) {
        int s = __shfl(idxA, ja);
        a0 += b2f(xp16[(size_t)s * 64 + lane]);
      }
      // drain B
      for (; jb + 8 <= degB; jb += 8) {
        int B0 = __shfl(idxB, jb + 0), B1 = __shfl(idxB, jb + 1);
        int B2 = __shfl(idxB, jb + 2), B3 = __shfl(idxB, jb + 3);
        int B4 = __shfl(idxB, jb + 4), B5 = __shfl(idxB, jb + 5);
        int B6 = __shfl(idxB, jb + 6), B7 = __shfl(idxB, jb + 7);
        unsigned short u0 = xp16[(size_t)B0 * 64 + lane];
        unsigned short u1 = xp16[(size_t)B1 * 64 + lane];
        unsigned short u2 = xp16[(size_t)B2 * 64 + lane];
        unsigned short u3 = xp16[(size_t)B3 * 64 + lane];
        unsigned short u4 = xp16[(size_t)B4 * 64 + lane];
        unsigned short u5 = xp16[(size_t)B5 * 64 + lane];
        unsigned short u6 = xp16[(size_t)B6 * 64 + lane];
        unsigned short u7 = xp16[(size_t)B7 * 64 + lane];
        c0 += b2f(u0) + b2f(u4);  c1 += b2f(u1) + b2f(u5);
        c2 += b2f(u2) + b2f(u6);  c3 += b2f(u3) + b2f(u7);
      }
      for (; jb + 4 <= degB; jb += 4) {
        int B0 = __shfl(idxB, jb + 0), B1 = __shfl(idxB, jb + 1);
        int B2 = __shfl(idxB, jb + 2), B3 = __shfl(idxB, jb + 3);
        c0 += b2f(xp16[(size_t)B0 * 64 + lane]);
        c1 += b2f(xp16[(size_t)B1 * 64 + lane]);
        c2 += b2f(xp16[(size_t)B2 * 64 + lane]);
        c3 += b2f(xp16[(size_t)B3 * 64 + lane]);
      }
      for (; jb < degB; ++jb) {
        int s = __shfl(idxB, jb);
        c0 += b2f(xp16[(size_t)s * 64 + lane]);
      }
    } else {
      agg_slow(xp16, src_s, begA, begB, lane, a0, a1, a2, a3);
      agg_slow(xp16, src_s, begB, endB, lane, c0, c1, c2, c3);
    }
    float vA = ((a0 + a1) + (a2 + a3)) * dinv[nA] + bias;
    float vB = ((c0 + c1) + (c2 + c3)) * dinv[nB] + bias;
    h2[(size_t)nA * 64 + lane] = f2b(vA);
    h2[(size_t)nB * 64 + lane] = f2b(vB);
    s1 += vA + vB;
    s2 += vA * vA + vB * vB;
  }
  __shared__ float ls[4][2][64];
  ls[wv][0][lane] = s1;
  ls[wv][1][lane] = s2;
  __syncthreads();
  if (wv == 0) {
    float a = ls[0][0][lane] + ls[1][0][lane] + ls[2][0][lane] + ls[3][0][lane];
    float b = ls[0][1][lane] + ls[1][1][lane] + ls[2][1][lane] + ls[3][1][lane];
    atomicAdd(&bnacc[lane], a);
    atomicAdd(&bnacc[64 + lane], b);
  }
}

// BN finalize -> affine form: a = gamma*istd, c = beta - mean*a
__global__ void bn_finalize_kernel(const float* __restrict__ bnacc,
                                   const float* __restrict__ gamma,
                                   const float* __restrict__ beta,
                                   float* __restrict__ bnac) {
  int ch = threadIdx.x;  // 64 threads
  float mean = bnacc[ch] * (1.0f / NN);
  float var = bnacc[64 + ch] * (1.0f / NN) - mean * mean;
  float istd = rsqrtf(var + 1e-5f);
  float a = gamma[ch] * istd;
  bnac[ch] = a;
  bnac[64 + ch] = beta[ch] - mean * a;
}

// ---------------- Output MLP: affine-BN -> Linear(64,128)+ReLU -> Linear(128,1) ----------

__global__ __launch_bounds__(256) void out_kernel(
    const unsigned short* __restrict__ x, const float* __restrict__ bnac,
    const float* __restrict__ W1, const float* __restrict__ b1,
    const float* __restrict__ W2, const float* __restrict__ b2,
    float* __restrict__ out) {
  __shared__ float sW1[64][128];
  __shared__ float sx[16][64];
  __shared__ float sz[16][128];
  __shared__ float sW2[128];
  int t = threadIdx.x;
  int row0 = blockIdx.x * 16;
#pragma unroll
  for (int j = 0; j < 32; ++j) {
    int e = t + 256 * j;
    sW1[e >> 7][e & 127] = W1[e];
  }
  if (t < 128) sW2[t] = W2[t];
  {
    int c64 = t & 63;
    float a = bnac[c64], c = bnac[64 + c64];
#pragma unroll
    for (int j = 0; j < 4; ++j) {
      int e = t + 256 * j;
      int r = e >> 6;
      int grow = row0 + r;
      float v = (grow < NN) ? b2f(x[(size_t)grow * 64 + c64]) : 0.f;
      sx[r][c64] = fmaf(v, a, c);   // BN, no ReLU (last layer)
    }
  }
  __syncthreads();

  int col = t & 127;
  int rg = t >> 7;
  float b1v = b1[col];
  float acc[8];
#pragma unroll
  for (int r = 0; r < 8; ++r) acc[r] = 0.f;
#pragma unroll 4
  for (int k = 0; k < 64; k += 4) {
    float w0 = sW1[k + 0][col], w1 = sW1[k + 1][col];
    float w2 = sW1[k + 2][col], w3 = sW1[k + 3][col];
#pragma unroll
    for (int r = 0; r < 8; ++r) {
      float4 xv = *(const float4*)&sx[rg * 8 + r][k];
      acc[r] = fmaf(xv.w, w3, fmaf(xv.z, w2, fmaf(xv.y, w1, fmaf(xv.x, w0, acc[r]))));
    }
  }
#pragma unroll
  for (int r = 0; r < 8; ++r) sz[rg * 8 + r][col] = fmaxf(acc[r] + b1v, 0.f);
  __syncthreads();

  {
    int row = t >> 4, g = t & 15;
    const float4* zr = (const float4*)&sz[row][0];
    const float4* wp = (const float4*)sW2;
    float4 z0 = zr[g * 2], z1 = zr[g * 2 + 1];
    float4 w0 = wp[g * 2], w1 = wp[g * 2 + 1];
    float p = z0.x * w0.x + z0.y * w0.y + z0.z * w0.z + z0.w * w0.w
            + z1.x * w1.x + z1.y * w1.y + z1.z * w1.z + z1.w * w1.w;
    p += __shfl_down(p, 8);
    p += __shfl_down(p, 4);
    p += __shfl_down(p, 2);
    p += __shfl_down(p, 1);
    int grow = row0 + row;
    if (g == 0 && grow < NN) out[grow] = p + b2[0];
  }
}

// ---------------- launch ----------------

extern "C" void kernel_launch(void* const* d_in, const int* in_sizes, int n_in,
                              void* d_out, int out_size, void* d_ws, size_t ws_size,
                              hipStream_t stream) {
  const float* X = (const float*)d_in[0];
  const int* edge = (const int*)d_in[1];
  const int* esrc = edge;
  const int* edst = edge + NE;
  const float* W_in = (const float*)d_in[2];
  const float* b_in = (const float*)d_in[3];
  const float* Ws = (const float*)d_in[4];
  const float* bs = (const float*)d_in[5];
  const float* gammas = (const float*)d_in[6];
  const float* betas = (const float*)d_in[7];
  const float* W1 = (const float*)d_in[8];
  const float* b1 = (const float*)d_in[9];
  const float* W2 = (const float*)d_in[10];
  const float* b2 = (const float*)d_in[11];
  float* out = (float*)d_out;

  char* base = (char*)d_ws;
  size_t o = 0;
  auto alloc = [&](size_t bytes) {
    o = (o + 255) & ~(size_t)255;
    void* p = base + o;
    o += bytes;
    return p;
  };
  int* counts = (int*)alloc((size_t)NN * 4);
  int* offsets = (int*)alloc((size_t)(NN + 1) * 4);
  int* blocksum = (int*)alloc(512 * 4);
  int* blockpfx = (int*)alloc(512 * 4);
  int* rank = (int*)alloc((size_t)NE * 4);
  int* src_s = (int*)alloc((size_t)NE * 4);
  float* dinv = (float*)alloc((size_t)NN * 4);
  unsigned short* bufA = (unsigned short*)alloc((size_t)NN * 64 * 2);
  unsigned short* bufB = (unsigned short*)alloc((size_t)NN * 64 * 2);
  unsigned short* hbuf16 = (unsigned short*)alloc((size_t)NN * 64 * 2);
  float* bnacc = (float*)alloc(3 * 128 * 4);
  float* bnpar = (float*)alloc(3 * 128 * 4);
  float* Wc = (float*)alloc(4096 * 4);
  float* bc = (float*)alloc(64 * 4);

  hipMemsetAsync(counts, 0, (size_t)NN * 4, stream);
  hipMemsetAsync(bnacc, 0, 3 * 128 * 4, stream);

  foldw_kernel<<<1, 256, 0, stream>>>(W_in, b_in, Ws, Wc, bc);
  count_rank_kernel<<<2048, 256, 0, stream>>>(edst, counts, rank);
  scan1_kernel<<<NB_SCAN, 256, 0, stream>>>(counts, offsets, blocksum, dinv);
  scan2_kernel<<<1, 512, 0, stream>>>(blocksum, blockpfx, offsets);
  scan3_kernel<<<NB_SCAN, 256, 0, stream>>>(offsets, blockpfx);
  scatter_kernel<<<2048, 256, 0, stream>>>(esrc, edst, offsets, rank, src_s);

  const int GEMM_GRID = (NN + 15) / 16;   // 6250
  unsigned short* xbufs[2] = {bufA, bufB};
  const unsigned short* xcur = nullptr;
  for (int i = 0; i < 3; ++i) {
    if (i == 0) {
      gemm64_kernel<<<GEMM_GRID, 256, 0, stream>>>(X, 0, Wc, bc, nullptr, dinv, hbuf16);
    } else {
      gemm64_kernel<<<GEMM_GRID, 256, 0, stream>>>(xcur, 1, Ws + (size_t)i * 64 * 64, nullptr,
                                                   bnpar + (size_t)(i - 1) * 128,
                                                   dinv, hbuf16);
    }
    unsigned short* xnext = xbufs[i & 1];
    agg_kernel<<<2048, 256, 0, stream>>>(hbuf16, offsets, src_s, dinv,
                                         bs + (size_t)i * 64, xnext,
                                         bnacc + (size_t)i * 128);
    bn_finalize_kernel<<<1, 64, 0, stream>>>(bnacc + (size_t)i * 128,
                                             gammas + (size_t)i * 64,
                                             betas + (size_t)i * 64,
                                             bnpar + (size_t)i * 128);
    xcur = xnext;
  }
  out_kernel<<<GEMM_GRID, 256, 0, stream>>>(xcur, bnpar + 2 * 128, W1, b1, W2, b2, out);
}

// Round 14
// 589.710 us; speedup vs baseline: 1.3361x; 1.0686x over previous
//
#include <hip/hip_runtime.h>

#define NN 100000
#define NE 1600000
#define NB_SCAN 391   // ceil(NN/256)

typedef __attribute__((ext_vector_type(8))) short bf16x8;
typedef __attribute__((ext_vector_type(4))) float f32x4;

// ---------------- bf16 helpers (manual, RNE) ----------------
__device__ inline float b2f(unsigned short u) {
  return __uint_as_float(((unsigned)u) << 16);
}
__device__ inline unsigned short f2b(float f) {
  unsigned x = __float_as_uint(f);
  unsigned r = (x + 0x7fffu + ((x >> 16) & 1u)) >> 16;
  return (unsigned short)r;
}

// ---------------- CSR build ----------------

__global__ void count_rank_kernel(const int* __restrict__ dst, int* __restrict__ counts,
                                  int* __restrict__ rank) {
  int i = blockIdx.x * blockDim.x + threadIdx.x;
  int st = gridDim.x * blockDim.x;
  for (; i < NE; i += st) rank[i] = atomicAdd(&counts[dst[i]], 1);
}

__global__ void scan1_kernel(const int* __restrict__ counts, int* __restrict__ offsets,
                             int* __restrict__ blocksum, float* __restrict__ dinv) {
  __shared__ int s[256];
  int t = threadIdx.x;
  int i = blockIdx.x * 256 + t;
  int v = (i < NN) ? counts[i] : 0;
  s[t] = v; __syncthreads();
  for (int off = 1; off < 256; off <<= 1) {
    int x = 0;
    if (t >= off) x = s[t - off];
    __syncthreads();
    if (t >= off) s[t] += x;
    __syncthreads();
  }
  if (i < NN) {
    offsets[i] = s[t] - v;
    dinv[i] = rsqrtf((float)v + 1.0f);
  }
  if (t == 255) blocksum[blockIdx.x] = s[255];
}

__global__ void scan2_kernel(const int* __restrict__ blocksum, int* __restrict__ blockpfx,
                             int* __restrict__ offsets) {
  __shared__ int s[512];
  int t = threadIdx.x;
  int v = (t < NB_SCAN) ? blocksum[t] : 0;
  s[t] = v; __syncthreads();
  for (int off = 1; off < 512; off <<= 1) {
    int x = 0;
    if (t >= off) x = s[t - off];
    __syncthreads();
    if (t >= off) s[t] += x;
    __syncthreads();
  }
  if (t < NB_SCAN) blockpfx[t] = s[t] - v;
  if (t == 511) offsets[NN] = s[511];
}

__global__ void scan3_kernel(int* __restrict__ offsets, const int* __restrict__ blockpfx) {
  int i = blockIdx.x * 256 + threadIdx.x;
  if (i < NN) offsets[i] += blockpfx[i >> 8];
}

__global__ void scatter_kernel(const int* __restrict__ src, const int* __restrict__ dst,
                               const int* __restrict__ offsets, const int* __restrict__ rank,
                               int* __restrict__ src_s) {
  int i = blockIdx.x * blockDim.x + threadIdx.x;
  int st = gridDim.x * blockDim.x;
  for (; i < NE; i += st) {
    int d = dst[i];
    src_s[offsets[d] + rank[i]] = src[i];
  }
}

// ---------------- fold input Linear into layer-0 weight ----------------
__global__ void foldw_kernel(const float* __restrict__ W_in, const float* __restrict__ b_in,
                             const float* __restrict__ W0,
                             float* __restrict__ Wc, float* __restrict__ bc) {
  int t = threadIdx.x;
  for (int e = t; e < 4096; e += 256) {
    int i = e >> 6, j = e & 63;
    float s = 0.f;
#pragma unroll
    for (int k = 0; k < 64; ++k) s += W_in[i * 64 + k] * W0[k * 64 + j];
    Wc[e] = s;
  }
  if (t < 64) {
    float s = 0.f;
#pragma unroll
    for (int k = 0; k < 64; ++k) s += b_in[k] * W0[k * 64 + t];
    bc[t] = s;
  }
}

// ---------------- X fp32 -> bf16 convert (one pass) ----------------
__global__ __launch_bounds__(256) void cvtx_kernel(const float4* __restrict__ X4,
                                                   ushort4* __restrict__ X16) {
  int i = blockIdx.x * blockDim.x + threadIdx.x;
  int st = gridDim.x * blockDim.x;
  for (; i < NN * 16; i += st) {
    float4 v = X4[i];
    ushort4 o;
    o.x = f2b(v.x); o.y = f2b(v.y); o.z = f2b(v.z); o.w = f2b(v.w);
    X16[i] = o;
  }
}

// ---------------- MFMA GEMM 64x64: bf16 in, fused affine-BN+ReLU, dinv scale, bf16 out ----
// 16x16x32 MFMA. Per wave: 16-row tile; A frag: lane holds x[row=(l&15)][k=(l>>4)*8..+7];
// B frags (W) held in VGPRs whole kernel: b[ct][kh][j] = W[kh*32+(l>>4)*8+j][ct*16+(l&15)];
// D: row=(l>>4)*4+reg, col=lane&15  [verified m89 mapping].

__global__ __launch_bounds__(256) void gemm_mfma_kernel(
    const unsigned short* __restrict__ x16,
    const float* __restrict__ W, const float* __restrict__ bias,
    const float* __restrict__ bnac, const float* __restrict__ dinv,
    unsigned short* __restrict__ out16) {
  __shared__ float sW[4096];
  int t = threadIdx.x;
  int lane = t & 63;
  int wv = t >> 6;
#pragma unroll
  for (int j = 0; j < 16; ++j) sW[t + 256 * j] = W[t + 256 * j];
  __syncthreads();
  int r16 = lane & 15;
  int g4 = lane >> 4;

  bf16x8 bf[4][2];
#pragma unroll
  for (int ct = 0; ct < 4; ++ct) {
#pragma unroll
    for (int kh = 0; kh < 2; ++kh) {
#pragma unroll
      for (int j = 0; j < 8; ++j) {
        int k = kh * 32 + g4 * 8 + j;
        bf[ct][kh][j] = (short)f2b(sW[k * 64 + ct * 16 + r16]);
      }
    }
  }
  float an[16], cn[16];
  if (bnac) {
#pragma unroll
    for (int kh = 0; kh < 2; ++kh) {
#pragma unroll
      for (int j = 0; j < 8; ++j) {
        int k = kh * 32 + g4 * 8 + j;
        an[kh * 8 + j] = bnac[k];
        cn[kh * 8 + j] = bnac[64 + k];
      }
    }
  }
  float bv[4];
#pragma unroll
  for (int ct = 0; ct < 4; ++ct) bv[ct] = bias ? bias[ct * 16 + r16] : 0.f;

  const int NT = NN / 16;  // 6250 exact
  int nw = gridDim.x * 4;
  for (int tile = blockIdx.x * 4 + wv; tile < NT; tile += nw) {
    int row0 = tile * 16;
    const unsigned short* xr = x16 + (size_t)(row0 + r16) * 64 + g4 * 8;
    bf16x8 alo = *(const bf16x8*)xr;
    bf16x8 ahi = *(const bf16x8*)(xr + 32);
    if (bnac) {
#pragma unroll
      for (int j = 0; j < 8; ++j) {
        float v = fmaxf(fmaf(b2f((unsigned short)alo[j]), an[j], cn[j]), 0.f);
        alo[j] = (short)f2b(v);
        float w = fmaxf(fmaf(b2f((unsigned short)ahi[j]), an[8 + j], cn[8 + j]), 0.f);
        ahi[j] = (short)f2b(w);
      }
    }
    float dv[4];
#pragma unroll
    for (int r = 0; r < 4; ++r) dv[r] = dinv[row0 + g4 * 4 + r];
#pragma unroll
    for (int ct = 0; ct < 4; ++ct) {
      f32x4 acc = {0.f, 0.f, 0.f, 0.f};
      acc = __builtin_amdgcn_mfma_f32_16x16x32_bf16(alo, bf[ct][0], acc, 0, 0, 0);
      acc = __builtin_amdgcn_mfma_f32_16x16x32_bf16(ahi, bf[ct][1], acc, 0, 0, 0);
#pragma unroll
      for (int r = 0; r < 4; ++r) {
        int grow = row0 + g4 * 4 + r;
        out16[(size_t)grow * 64 + ct * 16 + r16] = f2b((acc[r] + bv[ct]) * dv[r]);
      }
    }
  }
}

// ---------------- Edge aggregation: 2 nodes/wave interleaved, 16 gathers in flight ----

__device__ __forceinline__ void agg_slow(const unsigned short* __restrict__ xp16,
                                         const int* __restrict__ src_s,
                                         int beg, int end, int lane,
                                         float& a0, float& a1, float& a2, float& a3) {
  int deg = end - beg, done = 0;
  while (done < deg) {
    int chunk = deg - done;
    if (chunk > 64) chunk = 64;
    int idx = (lane < chunk) ? src_s[beg + done + lane] : 0;
    int j = 0;
    for (; j + 4 <= chunk; j += 4) {
      int t0 = __shfl(idx, j + 0), t1 = __shfl(idx, j + 1);
      int t2 = __shfl(idx, j + 2), t3 = __shfl(idx, j + 3);
      a0 += b2f(xp16[(size_t)t0 * 64 + lane]);
      a1 += b2f(xp16[(size_t)t1 * 64 + lane]);
      a2 += b2f(xp16[(size_t)t2 * 64 + lane]);
      a3 += b2f(xp16[(size_t)t3 * 64 + lane]);
    }
    for (; j < chunk; ++j) {
      int s = __shfl(idx, j);
      a0 += b2f(xp16[(size_t)s * 64 + lane]);
    }
    done += chunk;
  }
}

__global__ __launch_bounds__(256) void agg_kernel(
    const unsigned short* __restrict__ xp16, const int* __restrict__ offsets,
    const int* __restrict__ src_s, const float* __restrict__ dinv,
    const float* __restrict__ bvec, unsigned short* __restrict__ h2,
    float* __restrict__ bnacc) {
  int t = threadIdx.x;
  int lane = t & 63;
  int wv = t >> 6;
  float bias = bvec[lane];
  float s1 = 0.f, s2 = 0.f;
  int gw = blockIdx.x * 4 + wv;
  int nw = gridDim.x * 4;
  const int NP = NN / 2;   // 50000 pairs (NN even)
  for (int p = gw; p < NP; p += nw) {
    int nA = 2 * p, nB = 2 * p + 1;
    int begA = offsets[nA];
    int begB = offsets[nA + 1];
    int endB = offsets[nA + 2];
    int degA = begB - begA, degB = endB - begB;
    float a0 = b2f(xp16[(size_t)nA * 64 + lane]), a1 = 0.f, a2 = 0.f, a3 = 0.f;
    float c0 = b2f(xp16[(size_t)nB * 64 + lane]), c1 = 0.f, c2 = 0.f, c3 = 0.f;
    if (degA <= 64 && degB <= 64) {
      int idxA = (lane < degA) ? src_s[begA + lane] : 0;
      int idxB = (lane < degB) ? src_s[begB + lane] : 0;
      int ja = 0, jb = 0;
      while (ja + 8 <= degA && jb + 8 <= degB) {
        int A0 = __shfl(idxA, ja + 0), A1 = __shfl(idxA, ja + 1);
        int A2 = __shfl(idxA, ja + 2), A3 = __shfl(idxA, ja + 3);
        int A4 = __shfl(idxA, ja + 4), A5 = __shfl(idxA, ja + 5);
        int A6 = __shfl(idxA, ja + 6), A7 = __shfl(idxA, ja + 7);
        int B0 = __shfl(idxB, jb + 0), B1 = __shfl(idxB, jb + 1);
        int B2 = __shfl(idxB, jb + 2), B3 = __shfl(idxB, jb + 3);
        int B4 = __shfl(idxB, jb + 4), B5 = __shfl(idxB, jb + 5);
        int B6 = __shfl(idxB, jb + 6), B7 = __shfl(idxB, jb + 7);
        unsigned short uA0 = xp16[(size_t)A0 * 64 + lane];
        unsigned short uA1 = xp16[(size_t)A1 * 64 + lane];
        unsigned short uA2 = xp16[(size_t)A2 * 64 + lane];
        unsigned short uA3 = xp16[(size_t)A3 * 64 + lane];
        unsigned short uA4 = xp16[(size_t)A4 * 64 + lane];
        unsigned short uA5 = xp16[(size_t)A5 * 64 + lane];
        unsigned short uA6 = xp16[(size_t)A6 * 64 + lane];
        unsigned short uA7 = xp16[(size_t)A7 * 64 + lane];
        unsigned short uB0 = xp16[(size_t)B0 * 64 + lane];
        unsigned short uB1 = xp16[(size_t)B1 * 64 + lane];
        unsigned short uB2 = xp16[(size_t)B2 * 64 + lane];
        unsigned short uB3 = xp16[(size_t)B3 * 64 + lane];
        unsigned short uB4 = xp16[(size_t)B4 * 64 + lane];
        unsigned short uB5 = xp16[(size_t)B5 * 64 + lane];
        unsigned short uB6 = xp16[(size_t)B6 * 64 + lane];
        unsigned short uB7 = xp16[(size_t)B7 * 64 + lane];
        a0 += b2f(uA0) + b2f(uA4);  a1 += b2f(uA1) + b2f(uA5);
        a2 += b2f(uA2) + b2f(uA6);  a3 += b2f(uA3) + b2f(uA7);
        c0 += b2f(uB0) + b2f(uB4);  c1 += b2f(uB1) + b2f(uB5);
        c2 += b2f(uB2) + b2f(uB6);  c3 += b2f(uB3) + b2f(uB7);
        ja += 8; jb += 8;
      }
      for (; ja + 8 <= degA; ja += 8) {
        int A0 = __shfl(idxA, ja + 0), A1 = __shfl(idxA, ja + 1);
        int A2 = __shfl(idxA, ja + 2), A3 = __shfl(idxA, ja + 3);
        int A4 = __shfl(idxA, ja + 4), A5 = __shfl(idxA, ja + 5);
        int A6 = __shfl(idxA, ja + 6), A7 = __shfl(idxA, ja + 7);
        unsigned short u0 = xp16[(size_t)A0 * 64 + lane];
        unsigned short u1 = xp16[(size_t)A1 * 64 + lane];
        unsigned short u2 = xp16[(size_t)A2 * 64 + lane];
        unsigned short u3 = xp16[(size_t)A3 * 64 + lane];
        unsigned short u4 = xp16[(size_t)A4 * 64 + lane];
        unsigned short u5 = xp16[(size_t)A5 * 64 + lane];
        unsigned short u6 = xp16[(size_t)A6 * 64 + lane];
        unsigned short u7 = xp16[(size_t)A7 * 64 + lane];
        a0 += b2f(u0) + b2f(u4);  a1 += b2f(u1) + b2f(u5);
        a2 += b2f(u2) + b2f(u6);  a3 += b2f(u3) + b2f(u7);
      }
      for (; ja + 4 <= degA; ja += 4) {
        int A0 = __shfl(idxA, ja + 0), A1 = __shfl(idxA, ja + 1);
        int A2 = __shfl(idxA, ja + 2), A3 = __shfl(idxA, ja + 3);
        a0 += b2f(xp16[(size_t)A0 * 64 + lane]);
        a1 += b2f(xp16[(size_t)A1 * 64 + lane]);
        a2 += b2f(xp16[(size_t)A2 * 64 + lane]);
        a3 += b2f(xp16[(size_t)A3 * 64 + lane]);
      }
      for (; ja < degA; ++ja) {
        int s = __shfl(idxA, ja);
        a0 += b2f(xp16[(size_t)s * 64 + lane]);
      }
      for (; jb + 8 <= degB; jb += 8) {
        int B0 = __shfl(idxB, jb + 0), B1 = __shfl(idxB, jb + 1);
        int B2 = __shfl(idxB, jb + 2), B3 = __shfl(idxB, jb + 3);
        int B4 = __shfl(idxB, jb + 4), B5 = __shfl(idxB, jb + 5);
        int B6 = __shfl(idxB, jb + 6), B7 = __shfl(idxB, jb + 7);
        unsigned short u0 = xp16[(size_t)B0 * 64 + lane];
        unsigned short u1 = xp16[(size_t)B1 * 64 + lane];
        unsigned short u2 = xp16[(size_t)B2 * 64 + lane];
        unsigned short u3 = xp16[(size_t)B3 * 64 + lane];
        unsigned short u4 = xp16[(size_t)B4 * 64 + lane];
        unsigned short u5 = xp16[(size_t)B5 * 64 + lane];
        unsigned short u6 = xp16[(size_t)B6 * 64 + lane];
        unsigned short u7 = xp16[(size_t)B7 * 64 + lane];
        c0 += b2f(u0) + b2f(u4);  c1 += b2f(u1) + b2f(u5);
        c2 += b2f(u2) + b2f(u6);  c3 += b2f(u3) + b2f(u7);
      }
      for (; jb + 4 <= degB; jb += 4) {
        int B0 = __shfl(idxB, jb + 0), B1 = __shfl(idxB, jb + 1);
        int B2 = __shfl(idxB, jb + 2), B3 = __shfl(idxB, jb + 3);
        c0 += b2f(xp16[(size_t)B0 * 64 + lane]);
        c1 += b2f(xp16[(size_t)B1 * 64 + lane]);
        c2 += b2f(xp16[(size_t)B2 * 64 + lane]);
        c3 += b2f(xp16[(size_t)B3 * 64 + lane]);
      }
      for (; jb < degB; ++jb) {
        int s = __shfl(idxB, jb);
        c0 += b2f(xp16[(size_t)s * 64 + lane]);
      }
    } else {
      agg_slow(xp16, src_s, begA, begB, lane, a0, a1, a2, a3);
      agg_slow(xp16, src_s, begB, endB, lane, c0, c1, c2, c3);
    }
    float vA = ((a0 + a1) + (a2 + a3)) * dinv[nA] + bias;
    float vB = ((c0 + c1) + (c2 + c3)) * dinv[nB] + bias;
    h2[(size_t)nA * 64 + lane] = f2b(vA);
    h2[(size_t)nB * 64 + lane] = f2b(vB);
    s1 += vA + vB;
    s2 += vA * vA + vB * vB;
  }
  __shared__ float ls[4][2][64];
  ls[wv][0][lane] = s1;
  ls[wv][1][lane] = s2;
  __syncthreads();
  if (wv == 0) {
    float a = ls[0][0][lane] + ls[1][0][lane] + ls[2][0][lane] + ls[3][0][lane];
    float b = ls[0][1][lane] + ls[1][1][lane] + ls[2][1][lane] + ls[3][1][lane];
    atomicAdd(&bnacc[lane], a);
    atomicAdd(&bnacc[64 + lane], b);
  }
}

// BN finalize -> affine form: a = gamma*istd, c = beta - mean*a
__global__ void bn_finalize_kernel(const float* __restrict__ bnacc,
                                   const float* __restrict__ gamma,
                                   const float* __restrict__ beta,
                                   float* __restrict__ bnac) {
  int ch = threadIdx.x;  // 64 threads
  float mean = bnacc[ch] * (1.0f / NN);
  float var = bnacc[64 + ch] * (1.0f / NN) - mean * mean;
  float istd = rsqrtf(var + 1e-5f);
  float a = gamma[ch] * istd;
  bnac[ch] = a;
  bnac[64 + ch] = beta[ch] - mean * a;
}

// ---------------- Output MLP: affine-BN -> Linear(64,128)+ReLU -> Linear(128,1) ----------

__global__ __launch_bounds__(256) void out_kernel(
    const unsigned short* __restrict__ x, const float* __restrict__ bnac,
    const float* __restrict__ W1, const float* __restrict__ b1,
    const float* __restrict__ W2, const float* __restrict__ b2,
    float* __restrict__ out) {
  __shared__ float sW1[64][128];
  __shared__ float sx[16][64];
  __shared__ float sz[16][128];
  __shared__ float sW2[128];
  int t = threadIdx.x;
  int row0 = blockIdx.x * 16;
#pragma unroll
  for (int j = 0; j < 32; ++j) {
    int e = t + 256 * j;
    sW1[e >> 7][e & 127] = W1[e];
  }
  if (t < 128) sW2[t] = W2[t];
  {
    int c64 = t & 63;
    float a = bnac[c64], c = bnac[64 + c64];
#pragma unroll
    for (int j = 0; j < 4; ++j) {
      int e = t + 256 * j;
      int r = e >> 6;
      int grow = row0 + r;
      float v = (grow < NN) ? b2f(x[(size_t)grow * 64 + c64]) : 0.f;
      sx[r][c64] = fmaf(v, a, c);   // BN, no ReLU (last layer)
    }
  }
  __syncthreads();

  int col = t & 127;
  int rg = t >> 7;
  float b1v = b1[col];
  float acc[8];
#pragma unroll
  for (int r = 0; r < 8; ++r) acc[r] = 0.f;
#pragma unroll 4
  for (int k = 0; k < 64; k += 4) {
    float w0 = sW1[k + 0][col], w1 = sW1[k + 1][col];
    float w2 = sW1[k + 2][col], w3 = sW1[k + 3][col];
#pragma unroll
    for (int r = 0; r < 8; ++r) {
      float4 xv = *(const float4*)&sx[rg * 8 + r][k];
      acc[r] = fmaf(xv.w, w3, fmaf(xv.z, w2, fmaf(xv.y, w1, fmaf(xv.x, w0, acc[r]))));
    }
  }
#pragma unroll
  for (int r = 0; r < 8; ++r) sz[rg * 8 + r][col] = fmaxf(acc[r] + b1v, 0.f);
  __syncthreads();

  {
    int row = t >> 4, g = t & 15;
    const float4* zr = (const float4*)&sz[row][0];
    const float4* wp = (const float4*)sW2;
    float4 z0 = zr[g * 2], z1 = zr[g * 2 + 1];
    float4 w0 = wp[g * 2], w1 = wp[g * 2 + 1];
    float p = z0.x * w0.x + z0.y * w0.y + z0.z * w0.z + z0.w * w0.w
            + z1.x * w1.x + z1.y * w1.y + z1.z * w1.z + z1.w * w1.w;
    p += __shfl_down(p, 8);
    p += __shfl_down(p, 4);
    p += __shfl_down(p, 2);
    p += __shfl_down(p, 1);
    int grow = row0 + row;
    if (g == 0 && grow < NN) out[grow] = p + b2[0];
  }
}

// ---------------- launch ----------------

extern "C" void kernel_launch(void* const* d_in, const int* in_sizes, int n_in,
                              void* d_out, int out_size, void* d_ws, size_t ws_size,
                              hipStream_t stream) {
  const float* X = (const float*)d_in[0];
  const int* edge = (const int*)d_in[1];
  const int* esrc = edge;
  const int* edst = edge + NE;
  const float* W_in = (const float*)d_in[2];
  const float* b_in = (const float*)d_in[3];
  const float* Ws = (const float*)d_in[4];
  const float* bs = (const float*)d_in[5];
  const float* gammas = (const float*)d_in[6];
  const float* betas = (const float*)d_in[7];
  const float* W1 = (const float*)d_in[8];
  const float* b1 = (const float*)d_in[9];
  const float* W2 = (const float*)d_in[10];
  const float* b2 = (const float*)d_in[11];
  float* out = (float*)d_out;

  char* base = (char*)d_ws;
  size_t o = 0;
  auto alloc = [&](size_t bytes) {
    o = (o + 255) & ~(size_t)255;
    void* p = base + o;
    o += bytes;
    return p;
  };
  int* counts = (int*)alloc((size_t)NN * 4);
  int* offsets = (int*)alloc((size_t)(NN + 1) * 4);
  int* blocksum = (int*)alloc(512 * 4);
  int* blockpfx = (int*)alloc(512 * 4);
  int* rank = (int*)alloc((size_t)NE * 4);
  int* src_s = (int*)alloc((size_t)NE * 4);
  float* dinv = (float*)alloc((size_t)NN * 4);
  unsigned short* X16 = (unsigned short*)alloc((size_t)NN * 64 * 2);
  unsigned short* bufA = (unsigned short*)alloc((size_t)NN * 64 * 2);
  unsigned short* bufB = (unsigned short*)alloc((size_t)NN * 64 * 2);
  unsigned short* hbuf16 = (unsigned short*)alloc((size_t)NN * 64 * 2);
  float* bnacc = (float*)alloc(3 * 128 * 4);
  float* bnpar = (float*)alloc(3 * 128 * 4);
  float* Wc = (float*)alloc(4096 * 4);
  float* bc = (float*)alloc(64 * 4);

  hipMemsetAsync(counts, 0, (size_t)NN * 4, stream);
  hipMemsetAsync(bnacc, 0, 3 * 128 * 4, stream);

  foldw_kernel<<<1, 256, 0, stream>>>(W_in, b_in, Ws, Wc, bc);
  cvtx_kernel<<<2048, 256, 0, stream>>>((const float4*)X, (ushort4*)X16);
  count_rank_kernel<<<2048, 256, 0, stream>>>(edst, counts, rank);
  scan1_kernel<<<NB_SCAN, 256, 0, stream>>>(counts, offsets, blocksum, dinv);
  scan2_kernel<<<1, 512, 0, stream>>>(blocksum, blockpfx, offsets);
  scan3_kernel<<<NB_SCAN, 256, 0, stream>>>(offsets, blockpfx);
  scatter_kernel<<<2048, 256, 0, stream>>>(esrc, edst, offsets, rank, src_s);

  const int GEMM_GRID = (NN + 15) / 16;   // 6250 (out_kernel)
  unsigned short* xbufs[2] = {bufA, bufB};
  const unsigned short* xcur = nullptr;
  for (int i = 0; i < 3; ++i) {
    if (i == 0) {
      gemm_mfma_kernel<<<1563, 256, 0, stream>>>(X16, Wc, bc, nullptr, dinv, hbuf16);
    } else {
      gemm_mfma_kernel<<<1563, 256, 0, stream>>>(xcur, Ws + (size_t)i * 64 * 64, nullptr,
                                                 bnpar + (size_t)(i - 1) * 128,
                                                 dinv, hbuf16);
    }
    unsigned short* xnext = xbufs[i & 1];
    agg_kernel<<<2048, 256, 0, stream>>>(hbuf16, offsets, src_s, dinv,
                                         bs + (size_t)i * 64, xnext,
                                         bnacc + (size_t)i * 128);
    bn_finalize_kernel<<<1, 64, 0, stream>>>(bnacc + (size_t)i * 128,
                                             gammas + (size_t)i * 64,
                                             betas + (size_t)i * 64,
                                             bnpar + (size_t)i * 128);
    xcur = xnext;
  }
  out_kernel<<<GEMM_GRID, 256, 0, stream>>>(xcur, bnpar + 2 * 128, W1, b1, W2, b2, out);
}

// Round 15
// 549.885 us; speedup vs baseline: 1.4328x; 1.0724x over previous
//
#include <hip/hip_runtime.h>

#define NN 100000
#define NE 1600000
#define NB_SCAN 391   // ceil(NN/256)

typedef __attribute__((ext_vector_type(8))) short bf16x8;
typedef __attribute__((ext_vector_type(4))) float f32x4;

// ---------------- bf16 helpers (manual, RNE) ----------------
__device__ inline float b2f(unsigned short u) {
  return __uint_as_float(((unsigned)u) << 16);
}
__device__ inline unsigned short f2b(float f) {
  unsigned x = __float_as_uint(f);
  unsigned r = (x + 0x7fffu + ((x >> 16) & 1u)) >> 16;
  return (unsigned short)r;
}

// ---------------- CSR build ----------------

__global__ void count_rank_kernel(const int* __restrict__ dst, int* __restrict__ counts,
                                  unsigned short* __restrict__ rank) {
  int i = blockIdx.x * blockDim.x + threadIdx.x;
  int st = gridDim.x * blockDim.x;
  for (; i < NE; i += st) rank[i] = (unsigned short)atomicAdd(&counts[dst[i]], 1);
}

__global__ void scan1_kernel(const int* __restrict__ counts, int* __restrict__ offsets,
                             int* __restrict__ blocksum, float* __restrict__ dinv) {
  __shared__ int s[256];
  int t = threadIdx.x;
  int i = blockIdx.x * 256 + t;
  int v = (i < NN) ? counts[i] : 0;
  s[t] = v; __syncthreads();
  for (int off = 1; off < 256; off <<= 1) {
    int x = 0;
    if (t >= off) x = s[t - off];
    __syncthreads();
    if (t >= off) s[t] += x;
    __syncthreads();
  }
  if (i < NN) {
    offsets[i] = s[t] - v;
    dinv[i] = rsqrtf((float)v + 1.0f);
  }
  if (t == 255) blocksum[blockIdx.x] = s[255];
}

__global__ void scan2_kernel(const int* __restrict__ blocksum, int* __restrict__ blockpfx,
                             int* __restrict__ offsets) {
  __shared__ int s[512];
  int t = threadIdx.x;
  int v = (t < NB_SCAN) ? blocksum[t] : 0;
  s[t] = v; __syncthreads();
  for (int off = 1; off < 512; off <<= 1) {
    int x = 0;
    if (t >= off) x = s[t - off];
    __syncthreads();
    if (t >= off) s[t] += x;
    __syncthreads();
  }
  if (t < NB_SCAN) blockpfx[t] = s[t] - v;
  if (t == 511) offsets[NN] = s[511];
}

__global__ void scan3_kernel(int* __restrict__ offsets, const int* __restrict__ blockpfx) {
  int i = blockIdx.x * 256 + threadIdx.x;
  if (i < NN) offsets[i] += blockpfx[i >> 8];
}

__global__ void scatter_kernel(const int* __restrict__ src, const int* __restrict__ dst,
                               const int* __restrict__ offsets,
                               const unsigned short* __restrict__ rank,
                               int* __restrict__ src_s) {
  int i = blockIdx.x * blockDim.x + threadIdx.x;
  int st = gridDim.x * blockDim.x;
  for (; i < NE; i += st) {
    int d = dst[i];
    src_s[offsets[d] + (int)rank[i]] = src[i];
  }
}

// ---------------- fold input Linear into layer-0 weight ----------------
__global__ void foldw_kernel(const float* __restrict__ W_in, const float* __restrict__ b_in,
                             const float* __restrict__ W0,
                             float* __restrict__ Wc, float* __restrict__ bc) {
  int t = threadIdx.x;
  for (int e = t; e < 4096; e += 256) {
    int i = e >> 6, j = e & 63;
    float s = 0.f;
#pragma unroll
    for (int k = 0; k < 64; ++k) s += W_in[i * 64 + k] * W0[k * 64 + j];
    Wc[e] = s;
  }
  if (t < 64) {
    float s = 0.f;
#pragma unroll
    for (int k = 0; k < 64; ++k) s += b_in[k] * W0[k * 64 + t];
    bc[t] = s;
  }
}

// ---------------- MFMA GEMM 64x64: fused inline-BN+ReLU, dinv scale, bf16 out ----
// 16x16x32 MFMA. A frag: lane holds x[row=(l&15)][k=(l>>4)*8..+7];
// B frags in VGPRs: b[ct][kh][j] = W[kh*32+(l>>4)*8+j][ct*16+(l&15)];
// D: row=(l>>4)*4+reg, col=lane&15  [verified m89 mapping].

__global__ __launch_bounds__(256) void gemm_mfma_kernel(
    const void* __restrict__ xin, int xbf16,
    const float* __restrict__ W, const float* __restrict__ bias,
    const float* __restrict__ bnacc, const float* __restrict__ gamma,
    const float* __restrict__ beta, const float* __restrict__ dinv,
    unsigned short* __restrict__ out16) {
  __shared__ float sW[4096];
  int t = threadIdx.x;
  int lane = t & 63;
  int wv = t >> 6;
#pragma unroll
  for (int j = 0; j < 16; ++j) sW[t + 256 * j] = W[t + 256 * j];
  __syncthreads();
  int r16 = lane & 15;
  int g4 = lane >> 4;

  bf16x8 bf[4][2];
#pragma unroll
  for (int ct = 0; ct < 4; ++ct) {
#pragma unroll
    for (int kh = 0; kh < 2; ++kh) {
#pragma unroll
      for (int j = 0; j < 8; ++j) {
        int k = kh * 32 + g4 * 8 + j;
        bf[ct][kh][j] = (short)f2b(sW[k * 64 + ct * 16 + r16]);
      }
    }
  }
  float an[16], cn[16];
  if (bnacc) {
#pragma unroll
    for (int kh = 0; kh < 2; ++kh) {
#pragma unroll
      for (int j = 0; j < 8; ++j) {
        int k = kh * 32 + g4 * 8 + j;
        float mean = bnacc[k] * (1.0f / NN);
        float var = bnacc[64 + k] * (1.0f / NN) - mean * mean;
        float a = gamma[k] * rsqrtf(var + 1e-5f);
        an[kh * 8 + j] = a;
        cn[kh * 8 + j] = beta[k] - mean * a;
      }
    }
  }
  float bv[4];
#pragma unroll
  for (int ct = 0; ct < 4; ++ct) bv[ct] = bias ? bias[ct * 16 + r16] : 0.f;

  const int NT = NN / 16;  // 6250 exact
  int nw = gridDim.x * 4;
  for (int tile = blockIdx.x * 4 + wv; tile < NT; tile += nw) {
    int row0 = tile * 16;
    bf16x8 alo, ahi;
    if (xbf16) {
      const unsigned short* xr = (const unsigned short*)xin + (size_t)(row0 + r16) * 64 + g4 * 8;
      alo = *(const bf16x8*)xr;
      ahi = *(const bf16x8*)(xr + 32);
    } else {
      const float* xr = (const float*)xin + (size_t)(row0 + r16) * 64 + g4 * 8;
      float4 f0 = *(const float4*)xr;
      float4 f1 = *(const float4*)(xr + 4);
      float4 f2_ = *(const float4*)(xr + 32);
      float4 f3_ = *(const float4*)(xr + 36);
      alo[0] = (short)f2b(f0.x); alo[1] = (short)f2b(f0.y);
      alo[2] = (short)f2b(f0.z); alo[3] = (short)f2b(f0.w);
      alo[4] = (short)f2b(f1.x); alo[5] = (short)f2b(f1.y);
      alo[6] = (short)f2b(f1.z); alo[7] = (short)f2b(f1.w);
      ahi[0] = (short)f2b(f2_.x); ahi[1] = (short)f2b(f2_.y);
      ahi[2] = (short)f2b(f2_.z); ahi[3] = (short)f2b(f2_.w);
      ahi[4] = (short)f2b(f3_.x); ahi[5] = (short)f2b(f3_.y);
      ahi[6] = (short)f2b(f3_.z); ahi[7] = (short)f2b(f3_.w);
    }
    if (bnacc) {
#pragma unroll
      for (int j = 0; j < 8; ++j) {
        float v = fmaxf(fmaf(b2f((unsigned short)alo[j]), an[j], cn[j]), 0.f);
        alo[j] = (short)f2b(v);
        float w = fmaxf(fmaf(b2f((unsigned short)ahi[j]), an[8 + j], cn[8 + j]), 0.f);
        ahi[j] = (short)f2b(w);
      }
    }
    float dv[4];
#pragma unroll
    for (int r = 0; r < 4; ++r) dv[r] = dinv[row0 + g4 * 4 + r];
#pragma unroll
    for (int ct = 0; ct < 4; ++ct) {
      f32x4 acc = {0.f, 0.f, 0.f, 0.f};
      acc = __builtin_amdgcn_mfma_f32_16x16x32_bf16(alo, bf[ct][0], acc, 0, 0, 0);
      acc = __builtin_amdgcn_mfma_f32_16x16x32_bf16(ahi, bf[ct][1], acc, 0, 0, 0);
#pragma unroll
      for (int r = 0; r < 4; ++r) {
        int grow = row0 + g4 * 4 + r;
        out16[(size_t)grow * 64 + ct * 16 + r16] = f2b((acc[r] + bv[ct]) * dv[r]);
      }
    }
  }
}

// ---------------- Edge aggregation: 2 nodes/wave interleaved, 16 gathers in flight ----

__device__ __forceinline__ void agg_slow(const unsigned short* __restrict__ xp16,
                                         const int* __restrict__ src_s,
                                         int beg, int end, int lane,
                                         float& a0, float& a1, float& a2, float& a3) {
  int deg = end - beg, done = 0;
  while (done < deg) {
    int chunk = deg - done;
    if (chunk > 64) chunk = 64;
    int idx = (lane < chunk) ? src_s[beg + done + lane] : 0;
    int j = 0;
    for (; j + 4 <= chunk; j += 4) {
      int t0 = __shfl(idx, j + 0), t1 = __shfl(idx, j + 1);
      int t2 = __shfl(idx, j + 2), t3 = __shfl(idx, j + 3);
      a0 += b2f(xp16[(size_t)t0 * 64 + lane]);
      a1 += b2f(xp16[(size_t)t1 * 64 + lane]);
      a2 += b2f(xp16[(size_t)t2 * 64 + lane]);
      a3 += b2f(xp16[(size_t)t3 * 64 + lane]);
    }
    for (; j < chunk; ++j) {
      int s = __shfl(idx, j);
      a0 += b2f(xp16[(size_t)s * 64 + lane]);
    }
    done += chunk;
  }
}

__global__ __launch_bounds__(256) void agg_kernel(
    const unsigned short* __restrict__ xp16, const int* __restrict__ offsets,
    const int* __restrict__ src_s, const float* __restrict__ dinv,
    const float* __restrict__ bvec, unsigned short* __restrict__ h2,
    float* __restrict__ bnacc) {
  int t = threadIdx.x;
  int lane = t & 63;
  int wv = t >> 6;
  float bias = bvec[lane];
  float s1 = 0.f, s2 = 0.f;
  int gw = blockIdx.x * 4 + wv;
  int nw = gridDim.x * 4;
  const int NP = NN / 2;   // 50000 pairs (NN even)
  for (int p = gw; p < NP; p += nw) {
    int nA = 2 * p, nB = 2 * p + 1;
    int begA = offsets[nA];
    int begB = offsets[nA + 1];
    int endB = offsets[nA + 2];
    int degA = begB - begA, degB = endB - begB;
    float a0 = b2f(xp16[(size_t)nA * 64 + lane]), a1 = 0.f, a2 = 0.f, a3 = 0.f;
    float c0 = b2f(xp16[(size_t)nB * 64 + lane]), c1 = 0.f, c2 = 0.f, c3 = 0.f;
    if (degA <= 64 && degB <= 64) {
      int idxA = (lane < degA) ? src_s[begA + lane] : 0;
      int idxB = (lane < degB) ? src_s[begB + lane] : 0;
      int ja = 0, jb = 0;
      while (ja + 8 <= degA && jb + 8 <= degB) {
        int A0 = __shfl(idxA, ja + 0), A1 = __shfl(idxA, ja + 1);
        int A2 = __shfl(idxA, ja + 2), A3 = __shfl(idxA, ja + 3);
        int A4 = __shfl(idxA, ja + 4), A5 = __shfl(idxA, ja + 5);
        int A6 = __shfl(idxA, ja + 6), A7 = __shfl(idxA, ja + 7);
        int B0 = __shfl(idxB, jb + 0), B1 = __shfl(idxB, jb + 1);
        int B2 = __shfl(idxB, jb + 2), B3 = __shfl(idxB, jb + 3);
        int B4 = __shfl(idxB, jb + 4), B5 = __shfl(idxB, jb + 5);
        int B6 = __shfl(idxB, jb + 6), B7 = __shfl(idxB, jb + 7);
        unsigned short uA0 = xp16[(size_t)A0 * 64 + lane];
        unsigned short uA1 = xp16[(size_t)A1 * 64 + lane];
        unsigned short uA2 = xp16[(size_t)A2 * 64 + lane];
        unsigned short uA3 = xp16[(size_t)A3 * 64 + lane];
        unsigned short uA4 = xp16[(size_t)A4 * 64 + lane];
        unsigned short uA5 = xp16[(size_t)A5 * 64 + lane];
        unsigned short uA6 = xp16[(size_t)A6 * 64 + lane];
        unsigned short uA7 = xp16[(size_t)A7 * 64 + lane];
        unsigned short uB0 = xp16[(size_t)B0 * 64 + lane];
        unsigned short uB1 = xp16[(size_t)B1 * 64 + lane];
        unsigned short uB2 = xp16[(size_t)B2 * 64 + lane];
        unsigned short uB3 = xp16[(size_t)B3 * 64 + lane];
        unsigned short uB4 = xp16[(size_t)B4 * 64 + lane];
        unsigned short uB5 = xp16[(size_t)B5 * 64 + lane];
        unsigned short uB6 = xp16[(size_t)B6 * 64 + lane];
        unsigned short uB7 = xp16[(size_t)B7 * 64 + lane];
        a0 += b2f(uA0) + b2f(uA4);  a1 += b2f(uA1) + b2f(uA5);
        a2 += b2f(uA2) + b2f(uA6);  a3 += b2f(uA3) + b2f(uA7);
        c0 += b2f(uB0) + b2f(uB4);  c1 += b2f(uB1) + b2f(uB5);
        c2 += b2f(uB2) + b2f(uB6);  c3 += b2f(uB3) + b2f(uB7);
        ja += 8; jb += 8;
      }
      for (; ja + 8 <= degA; ja += 8) {
        int A0 = __shfl(idxA, ja + 0), A1 = __shfl(idxA, ja + 1);
        int A2 = __shfl(idxA, ja + 2), A3 = __shfl(idxA, ja + 3);
        int A4 = __shfl(idxA, ja + 4), A5 = __shfl(idxA, ja + 5);
        int A6 = __shfl(idxA, ja + 6), A7 = __shfl(idxA, ja + 7);
        unsigned short u0 = xp16[(size_t)A0 * 64 + lane];
        unsigned short u1 = xp16[(size_t)A1 * 64 + lane];
        unsigned short u2 = xp16[(size_t)A2 * 64 + lane];
        unsigned short u3 = xp16[(size_t)A3 * 64 + lane];
        unsigned short u4 = xp16[(size_t)A4 * 64 + lane];
        unsigned short u5 = xp16[(size_t)A5 * 64 + lane];
        unsigned short u6 = xp16[(size_t)A6 * 64 + lane];
        unsigned short u7 = xp16[(size_t)A7 * 64 + lane];
        a0 += b2f(u0) + b2f(u4);  a1 += b2f(u1) + b2f(u5);
        a2 += b2f(u2) + b2f(u6);  a3 += b2f(u3) + b2f(u7);
      }
      for (; ja + 4 <= degA; ja += 4) {
        int A0 = __shfl(idxA, ja + 0), A1 = __shfl(idxA, ja + 1);
        int A2 = __shfl(idxA, ja + 2), A3 = __shfl(idxA, ja + 3);
        a0 += b2f(xp16[(size_t)A0 * 64 + lane]);
        a1 += b2f(xp16[(size_t)A1 * 64 + lane]);
        a2 += b2f(xp16[(size_t)A2 * 64 + lane]);
        a3 += b2f(xp16[(size_t)A3 * 64 + lane]);
      }
      for (; ja < degA; ++ja) {
        int s = __shfl(idxA, ja);
        a0 += b2f(xp16[(size_t)s * 64 + lane]);
      }
      for (; jb + 8 <= degB; jb += 8) {
        int B0 = __shfl(idxB, jb + 0), B1 = __shfl(idxB, jb + 1);
        int B2 = __shfl(idxB, jb + 2), B3 = __shfl(idxB, jb + 3);
        int B4 = __shfl(idxB, jb + 4), B5 = __shfl(idxB, jb + 5);
        int B6 = __shfl(idxB, jb + 6), B7 = __shfl(idxB, jb + 7);
        unsigned short u0 = xp16[(size_t)B0 * 64 + lane];
        unsigned short u1 = xp16[(size_t)B1 * 64 + lane];
        unsigned short u2 = xp16[(size_t)B2 * 64 + lane];
        unsigned short u3 = xp16[(size_t)B3 * 64 + lane];
        unsigned short u4 = xp16[(size_t)B4 * 64 + lane];
        unsigned short u5 = xp16[(size_t)B5 * 64 + lane];
        unsigned short u6 = xp16[(size_t)B6 * 64 + lane];
        unsigned short u7 = xp16[(size_t)B7 * 64 + lane];
        c0 += b2f(u0) + b2f(u4);  c1 += b2f(u1) + b2f(u5);
        c2 += b2f(u2) + b2f(u6);  c3 += b2f(u3) + b2f(u7);
      }
      for (; jb + 4 <= degB; jb += 4) {
        int B0 = __shfl(idxB, jb + 0), B1 = __shfl(idxB, jb + 1);
        int B2 = __shfl(idxB, jb + 2), B3 = __shfl(idxB, jb + 3);
        c0 += b2f(xp16[(size_t)B0 * 64 + lane]);
        c1 += b2f(xp16[(size_t)B1 * 64 + lane]);
        c2 += b2f(xp16[(size_t)B2 * 64 + lane]);
        c3 += b2f(xp16[(size_t)B3 * 64 + lane]);
      }
      for (; jb < degB; ++jb) {
        int s = __shfl(idxB, jb);
        c0 += b2f(xp16[(size_t)s * 64 + lane]);
      }
    } else {
      agg_slow(xp16, src_s, begA, begB, lane, a0, a1, a2, a3);
      agg_slow(xp16, src_s, begB, endB, lane, c0, c1, c2, c3);
    }
    float vA = ((a0 + a1) + (a2 + a3)) * dinv[nA] + bias;
    float vB = ((c0 + c1) + (c2 + c3)) * dinv[nB] + bias;
    h2[(size_t)nA * 64 + lane] = f2b(vA);
    h2[(size_t)nB * 64 + lane] = f2b(vB);
    s1 += vA + vB;
    s2 += vA * vA + vB * vB;
  }
  __shared__ float ls[4][2][64];
  ls[wv][0][lane] = s1;
  ls[wv][1][lane] = s2;
  __syncthreads();
  if (wv == 0) {
    float a = ls[0][0][lane] + ls[1][0][lane] + ls[2][0][lane] + ls[3][0][lane];
    float b = ls[0][1][lane] + ls[1][1][lane] + ls[2][1][lane] + ls[3][1][lane];
    atomicAdd(&bnacc[lane], a);
    atomicAdd(&bnacc[64 + lane], b);
  }
}

// ---------------- MFMA Output MLP: inline-BN -> Lin(64,128)+ReLU -> Lin(128,1) ----------
// Phase1 x@W1 via MFMA (same frag mapping); phase2 per-lane partial dot + shfl_xor reduce.

__global__ __launch_bounds__(256) void out_mfma_kernel(
    const unsigned short* __restrict__ x16,
    const float* __restrict__ bnacc, const float* __restrict__ gamma,
    const float* __restrict__ beta,
    const float* __restrict__ W1, const float* __restrict__ b1,
    const float* __restrict__ W2, const float* __restrict__ b2,
    float* __restrict__ out) {
  __shared__ float sW1[8192];
  int t = threadIdx.x;
  int lane = t & 63;
  int wv = t >> 6;
#pragma unroll
  for (int j = 0; j < 32; ++j) sW1[t + 256 * j] = W1[t + 256 * j];
  __syncthreads();
  int r16 = lane & 15;
  int g4 = lane >> 4;

  bf16x8 bw[8][2];
#pragma unroll
  for (int ct = 0; ct < 8; ++ct) {
#pragma unroll
    for (int kh = 0; kh < 2; ++kh) {
#pragma unroll
      for (int j = 0; j < 8; ++j) {
        int k = kh * 32 + g4 * 8 + j;
        bw[ct][kh][j] = (short)f2b(sW1[k * 128 + ct * 16 + r16]);
      }
    }
  }
  float an[16], cn[16];
#pragma unroll
  for (int kh = 0; kh < 2; ++kh) {
#pragma unroll
    for (int j = 0; j < 8; ++j) {
      int k = kh * 32 + g4 * 8 + j;
      float mean = bnacc[k] * (1.0f / NN);
      float var = bnacc[64 + k] * (1.0f / NN) - mean * mean;
      float a = gamma[k] * rsqrtf(var + 1e-5f);
      an[kh * 8 + j] = a;
      cn[kh * 8 + j] = beta[k] - mean * a;
    }
  }
  float b1v[8], w2v[8];
#pragma unroll
  for (int ct = 0; ct < 8; ++ct) {
    b1v[ct] = b1[ct * 16 + r16];
    w2v[ct] = W2[ct * 16 + r16];
  }
  float bias2 = b2[0];

  const int NT = NN / 16;  // 6250
  int nw = gridDim.x * 4;
  for (int tile = blockIdx.x * 4 + wv; tile < NT; tile += nw) {
    int row0 = tile * 16;
    const unsigned short* xr = x16 + (size_t)(row0 + r16) * 64 + g4 * 8;
    bf16x8 alo = *(const bf16x8*)xr;
    bf16x8 ahi = *(const bf16x8*)(xr + 32);
#pragma unroll
    for (int j = 0; j < 8; ++j) {   // BN affine, NO ReLU (last layer)
      alo[j] = (short)f2b(fmaf(b2f((unsigned short)alo[j]), an[j], cn[j]));
      ahi[j] = (short)f2b(fmaf(b2f((unsigned short)ahi[j]), an[8 + j], cn[8 + j]));
    }
    float p0 = 0.f, p1 = 0.f, p2 = 0.f, p3 = 0.f;
#pragma unroll
    for (int ct = 0; ct < 8; ++ct) {
      f32x4 acc = {0.f, 0.f, 0.f, 0.f};
      acc = __builtin_amdgcn_mfma_f32_16x16x32_bf16(alo, bw[ct][0], acc, 0, 0, 0);
      acc = __builtin_amdgcn_mfma_f32_16x16x32_bf16(ahi, bw[ct][1], acc, 0, 0, 0);
      p0 += fmaxf(acc[0] + b1v[ct], 0.f) * w2v[ct];
      p1 += fmaxf(acc[1] + b1v[ct], 0.f) * w2v[ct];
      p2 += fmaxf(acc[2] + b1v[ct], 0.f) * w2v[ct];
      p3 += fmaxf(acc[3] + b1v[ct], 0.f) * w2v[ct];
    }
    // reduce over the 16 lanes (r16) of each g4 group
#pragma unroll
    for (int m = 1; m < 16; m <<= 1) {
      p0 += __shfl_xor(p0, m);
      p1 += __shfl_xor(p1, m);
      p2 += __shfl_xor(p2, m);
      p3 += __shfl_xor(p3, m);
    }
    if (r16 == 0) {
      int rbase = row0 + g4 * 4;
      out[rbase + 0] = p0 + bias2;
      out[rbase + 1] = p1 + bias2;
      out[rbase + 2] = p2 + bias2;
      out[rbase + 3] = p3 + bias2;
    }
  }
}

// ---------------- launch ----------------

extern "C" void kernel_launch(void* const* d_in, const int* in_sizes, int n_in,
                              void* d_out, int out_size, void* d_ws, size_t ws_size,
                              hipStream_t stream) {
  const float* X = (const float*)d_in[0];
  const int* edge = (const int*)d_in[1];
  const int* esrc = edge;
  const int* edst = edge + NE;
  const float* W_in = (const float*)d_in[2];
  const float* b_in = (const float*)d_in[3];
  const float* Ws = (const float*)d_in[4];
  const float* bs = (const float*)d_in[5];
  const float* gammas = (const float*)d_in[6];
  const float* betas = (const float*)d_in[7];
  const float* W1 = (const float*)d_in[8];
  const float* b1 = (const float*)d_in[9];
  const float* W2 = (const float*)d_in[10];
  const float* b2 = (const float*)d_in[11];
  float* out = (float*)d_out;

  char* base = (char*)d_ws;
  size_t o = 0;
  auto alloc = [&](size_t bytes) {
    o = (o + 255) & ~(size_t)255;
    void* p = base + o;
    o += bytes;
    return p;
  };
  int* counts = (int*)alloc((size_t)NN * 4);
  int* offsets = (int*)alloc((size_t)(NN + 1) * 4);
  int* blocksum = (int*)alloc(512 * 4);
  int* blockpfx = (int*)alloc(512 * 4);
  unsigned short* rank = (unsigned short*)alloc((size_t)NE * 2);
  int* src_s = (int*)alloc((size_t)NE * 4);
  float* dinv = (float*)alloc((size_t)NN * 4);
  unsigned short* bufA = (unsigned short*)alloc((size_t)NN * 64 * 2);
  unsigned short* bufB = (unsigned short*)alloc((size_t)NN * 64 * 2);
  unsigned short* hbuf16 = (unsigned short*)alloc((size_t)NN * 64 * 2);
  float* bnacc = (float*)alloc(3 * 128 * 4);
  float* Wc = (float*)alloc(4096 * 4);
  float* bc = (float*)alloc(64 * 4);

  hipMemsetAsync(counts, 0, (size_t)NN * 4, stream);
  hipMemsetAsync(bnacc, 0, 3 * 128 * 4, stream);

  foldw_kernel<<<1, 256, 0, stream>>>(W_in, b_in, Ws, Wc, bc);
  count_rank_kernel<<<2048, 256, 0, stream>>>(edst, counts, rank);
  scan1_kernel<<<NB_SCAN, 256, 0, stream>>>(counts, offsets, blocksum, dinv);
  scan2_kernel<<<1, 512, 0, stream>>>(blocksum, blockpfx, offsets);
  scan3_kernel<<<NB_SCAN, 256, 0, stream>>>(offsets, blockpfx);
  scatter_kernel<<<2048, 256, 0, stream>>>(esrc, edst, offsets, rank, src_s);

  unsigned short* xbufs[2] = {bufA, bufB};
  const unsigned short* xcur = nullptr;
  for (int i = 0; i < 3; ++i) {
    if (i == 0) {
      gemm_mfma_kernel<<<1563, 256, 0, stream>>>(X, 0, Wc, bc, nullptr, nullptr, nullptr,
                                                 dinv, hbuf16);
    } else {
      gemm_mfma_kernel<<<1563, 256, 0, stream>>>(xcur, 1, Ws + (size_t)i * 64 * 64, nullptr,
                                                 bnacc + (size_t)(i - 1) * 128,
                                                 gammas + (size_t)(i - 1) * 64,
                                                 betas + (size_t)(i - 1) * 64,
                                                 dinv, hbuf16);
    }
    unsigned short* xnext = xbufs[i & 1];
    agg_kernel<<<2048, 256, 0, stream>>>(hbuf16, offsets, src_s, dinv,
                                         bs + (size_t)i * 64, xnext,
                                         bnacc + (size_t)i * 128);
    xcur = xnext;
  }
  out_mfma_kernel<<<1563, 256, 0, stream>>>(xcur, bnacc + 2 * 128, gammas + 2 * 64,
                                            betas + 2 * 64, W1, b1, W2, b2, out);
}